// Round 2
// baseline (895.405 us; speedup 1.0000x reference)
//
#include <hip/hip_runtime.h>
#include <hip/hip_bf16.h>

#define N_USERS 200000
#define N_ITEMS 100000
#define N_NODES 300000
#define N_EDGES 4800000
#define EMB 64
#define BATCH 4096
#define NSLOTS (2 * BATCH)

typedef unsigned int u32;

// K1: re-init workspace every call (harness poisons ws with 0xAA before each launch)
__global__ void k_init(int* __restrict__ node2slot, float* __restrict__ acc, u32* __restrict__ counter) {
    int i = blockIdx.x * blockDim.x + threadIdx.x;
    if (i < N_NODES) node2slot[i] = -1;
    if (i < NSLOTS * EMB) acc[i] = 0.f;
    if (i == 0) *counter = 0u;
}

// K2: mark selected nodes with a canonical output slot (duplicates share winner)
__global__ void k_map(const int* __restrict__ user_id, const int* __restrict__ item_id,
                      int* __restrict__ node2slot) {
    int b = blockIdx.x * blockDim.x + threadIdx.x;
    if (b >= NSLOTS) return;
    int node = (b < BATCH) ? user_id[b] : (N_USERS + item_id[b - BATCH]);
    atomicCAS(&node2slot[node], -1, b);
}

// K3: stream all edges once, enqueue edges whose row is selected (~2.7% hit rate)
__global__ void k_filter(const int* __restrict__ adj_row, const int* __restrict__ node2slot,
                         u32* __restrict__ counter, u32* __restrict__ hits, u32 cap) {
    int e = blockIdx.x * blockDim.x + threadIdx.x;
    if (e >= N_EDGES) return;
    int r = adj_row[e];
    if (node2slot[r] >= 0) {
        u32 p = atomicAdd(counter, 1u);
        if (p < cap) hits[p] = (u32)e;
    }
}

// K4: one wave per hit edge; lane k accumulates feature k
__global__ void k_acc(const u32* __restrict__ counter, const u32* __restrict__ hits, u32 cap,
                      const int* __restrict__ adj_row, const int* __restrict__ adj_col,
                      const float* __restrict__ vals,
                      const float* __restrict__ user_emb,
                      const float* __restrict__ item_emb,
                      const int* __restrict__ node2slot, float* __restrict__ acc) {
    u32 nh = *counter;
    if (nh > cap) nh = cap;
    int lane = threadIdx.x & 63;
    u32 wave = (u32)(blockIdx.x * blockDim.x + threadIdx.x) >> 6;
    u32 nwaves = (u32)(gridDim.x * blockDim.x) >> 6;
    for (u32 h = wave; h < nh; h += nwaves) {
        u32 e = hits[h];
        int r = adj_row[e];
        int s = node2slot[r];      // node2slot is L2-hot (1.2 MB)
        int c = adj_col[e];
        float v = vals[e];
        const float* xr = (c < N_USERS) ? (user_emb + (size_t)c * EMB)
                                        : (item_emb + (size_t)(c - N_USERS) * EMB);
        float x = xr[lane];        // 256B coalesced f32 row read
        atomicAdd(&acc[(size_t)s * EMB + lane], v * x);  // 256B coalesced f32 atomic, L2-resident
    }
}

// K5: out[o] = 2*x0[node] + acc[canonical_slot(node)]
__global__ void k_out(const int* __restrict__ user_id, const int* __restrict__ item_id,
                      const int* __restrict__ node2slot, const float* __restrict__ acc,
                      const float* __restrict__ user_emb,
                      const float* __restrict__ item_emb,
                      float* __restrict__ out) {
    int t = blockIdx.x * blockDim.x + threadIdx.x;
    int o = t >> 6, lane = t & 63;
    if (o >= NSLOTS) return;
    int node = (o < BATCH) ? user_id[o] : (N_USERS + item_id[o - BATCH]);
    int s = node2slot[node];
    const float* xr = (node < N_USERS) ? (user_emb + (size_t)node * EMB)
                                       : (item_emb + (size_t)(node - N_USERS) * EMB);
    out[(size_t)o * EMB + lane] = 2.f * xr[lane] + acc[(size_t)s * EMB + lane];
}

extern "C" void kernel_launch(void* const* d_in, const int* in_sizes, int n_in,
                              void* d_out, int out_size, void* d_ws, size_t ws_size,
                              hipStream_t stream) {
    const float* user_emb = (const float*)d_in[0];
    const float* item_emb = (const float*)d_in[1];
    const int* adj_row = (const int*)d_in[2];
    const int* adj_col = (const int*)d_in[3];
    const float* adj_vals = (const float*)d_in[4];
    const int* user_id = (const int*)d_in[5];
    const int* item_id = (const int*)d_in[6];
    float* out = (float*)d_out;

    // workspace layout (256B aligned): node2slot 1.2MB | counter | acc 2MB | hits (rest)
    char* ws = (char*)d_ws;
    size_t off = 0;
    int* node2slot = (int*)(ws + off);      off += ((size_t)N_NODES * 4 + 255) & ~(size_t)255;
    u32* counter   = (u32*)(ws + off);      off += 256;
    float* acc     = (float*)(ws + off);    off += ((size_t)NSLOTS * EMB * 4 + 255) & ~(size_t)255;
    u32* hits      = (u32*)(ws + off);
    u32 cap = (ws_size > off + 4) ? (u32)((ws_size - off) / 4) : 0u;
    if (cap > (u32)N_EDGES) cap = (u32)N_EDGES;

    const int B = 256;
    int init_range = (N_NODES > NSLOTS * EMB) ? N_NODES : NSLOTS * EMB;
    k_init<<<(init_range + B - 1) / B, B, 0, stream>>>(node2slot, acc, counter);
    k_map<<<(NSLOTS + B - 1) / B, B, 0, stream>>>(user_id, item_id, node2slot);
    k_filter<<<(N_EDGES + B - 1) / B, B, 0, stream>>>(adj_row, node2slot, counter, hits, cap);
    k_acc<<<1024, B, 0, stream>>>(counter, hits, cap, adj_row, adj_col, adj_vals,
                                  user_emb, item_emb, node2slot, acc);
    k_out<<<(NSLOTS * EMB + B - 1) / B, B, 0, stream>>>(user_id, item_id, node2slot, acc,
                                                        user_emb, item_emb, out);
}

// Round 3
// 191.753 us; speedup vs baseline: 4.6696x; 4.6696x over previous
//
#include <hip/hip_runtime.h>
#include <hip/hip_bf16.h>

#define N_USERS 200000
#define N_ITEMS 100000
#define N_NODES 300000
#define N_EDGES 4800000
#define EMB 64
#define BATCH 4096
#define NSLOTS (2 * BATCH)
#define NBITMAP ((N_NODES + 31) / 32)   // 9375 u32 = 37.5 KB

typedef unsigned int u32;

// K1: re-init workspace every call (harness poisons ws with 0xAA)
__global__ void k_init(int* __restrict__ node2slot, float* __restrict__ acc, u32* __restrict__ bitmap) {
    int i = blockIdx.x * blockDim.x + threadIdx.x;
    if (i < N_NODES) node2slot[i] = -1;
    if (i < NSLOTS * EMB) acc[i] = 0.f;
    if (i < NBITMAP) bitmap[i] = 0u;
}

// K2: mark selected nodes: canonical slot (CAS, duplicates share winner) + membership bit
__global__ void k_map(const int* __restrict__ user_id, const int* __restrict__ item_id,
                      int* __restrict__ node2slot, u32* __restrict__ bitmap) {
    int b = blockIdx.x * blockDim.x + threadIdx.x;
    if (b >= NSLOTS) return;
    int node = (b < BATCH) ? user_id[b] : (N_USERS + item_id[b - BATCH]);
    atomicCAS(&node2slot[node], -1, b);
    atomicOr(&bitmap[node >> 5], 1u << (node & 31));
}

// K3 (fused filter+accumulate): one wave handles 64 edges/iter; membership via L1-hot
// bitmap; hit edges processed wave-cooperatively (lane k = feature k). No global counter.
__global__ void k_fused(const int* __restrict__ adj_row, const int* __restrict__ adj_col,
                        const float* __restrict__ vals,
                        const float* __restrict__ user_emb,
                        const float* __restrict__ item_emb,
                        const u32* __restrict__ bitmap,
                        const int* __restrict__ node2slot,
                        float* __restrict__ acc) {
    int lane = threadIdx.x & 63;
    u32 wave = (u32)(blockIdx.x * blockDim.x + threadIdx.x) >> 6;
    u32 nwaves = (u32)(gridDim.x * blockDim.x) >> 6;
    for (u32 base = wave * 64; base < N_EDGES; base += nwaves * 64) {
        u32 e = base + (u32)lane;
        int r = (e < N_EDGES) ? adj_row[e] : 0;                 // coalesced 256B
        bool hit = (e < N_EDGES) && ((bitmap[r >> 5] >> (r & 31)) & 1u);  // L1-hot 37.5KB
        unsigned long long m = __ballot(hit);                   // avg ~1.75 bits set
        while (m) {
            int src = __ffsll((long long)m) - 1;
            m &= m - 1;
            u32 eh = base + (u32)src;
            int rh = __shfl(r, src);
            int s = node2slot[rh];          // same-addr broadcast load, L2-hot
            int c = adj_col[eh];            // same-addr broadcast
            float v = vals[eh];             // same-addr broadcast
            const float* xr = (c < N_USERS) ? (user_emb + (size_t)c * EMB)
                                            : (item_emb + (size_t)(c - N_USERS) * EMB);
            atomicAdd(&acc[(size_t)s * EMB + lane], v * xr[lane]);  // 256B coalesced, L2-resident
        }
    }
}

// K4: out[o] = 2*x0[node] + acc[canonical_slot(node)]
__global__ void k_out(const int* __restrict__ user_id, const int* __restrict__ item_id,
                      const int* __restrict__ node2slot, const float* __restrict__ acc,
                      const float* __restrict__ user_emb,
                      const float* __restrict__ item_emb,
                      float* __restrict__ out) {
    int t = blockIdx.x * blockDim.x + threadIdx.x;
    int o = t >> 6, lane = t & 63;
    if (o >= NSLOTS) return;
    int node = (o < BATCH) ? user_id[o] : (N_USERS + item_id[o - BATCH]);
    int s = node2slot[node];
    const float* xr = (node < N_USERS) ? (user_emb + (size_t)node * EMB)
                                       : (item_emb + (size_t)(node - N_USERS) * EMB);
    out[(size_t)o * EMB + lane] = 2.f * xr[lane] + acc[(size_t)s * EMB + lane];
}

extern "C" void kernel_launch(void* const* d_in, const int* in_sizes, int n_in,
                              void* d_out, int out_size, void* d_ws, size_t ws_size,
                              hipStream_t stream) {
    const float* user_emb = (const float*)d_in[0];
    const float* item_emb = (const float*)d_in[1];
    const int* adj_row = (const int*)d_in[2];
    const int* adj_col = (const int*)d_in[3];
    const float* adj_vals = (const float*)d_in[4];
    const int* user_id = (const int*)d_in[5];
    const int* item_id = (const int*)d_in[6];
    float* out = (float*)d_out;

    // ws layout (256B aligned): node2slot 1.2MB | acc 2MB | bitmap 37.5KB
    char* ws = (char*)d_ws;
    size_t off = 0;
    int* node2slot = (int*)(ws + off);   off += ((size_t)N_NODES * 4 + 255) & ~(size_t)255;
    float* acc     = (float*)(ws + off); off += ((size_t)NSLOTS * EMB * 4 + 255) & ~(size_t)255;
    u32* bitmap    = (u32*)(ws + off);

    const int B = 256;
    int init_range = (N_NODES > NSLOTS * EMB) ? N_NODES : NSLOTS * EMB;
    k_init<<<(init_range + B - 1) / B, B, 0, stream>>>(node2slot, acc, bitmap);
    k_map<<<(NSLOTS + B - 1) / B, B, 0, stream>>>(user_id, item_id, node2slot, bitmap);
    // 2048 blocks x 256 = 8192 waves; grid-stride over 75k wave-chunks of 64 edges
    k_fused<<<2048, B, 0, stream>>>(adj_row, adj_col, adj_vals, user_emb, item_emb,
                                    bitmap, node2slot, acc);
    k_out<<<(NSLOTS * EMB + B - 1) / B, B, 0, stream>>>(user_id, item_id, node2slot, acc,
                                                        user_emb, item_emb, out);
}

// Round 4
// 175.880 us; speedup vs baseline: 5.0910x; 1.0902x over previous
//
#include <hip/hip_runtime.h>

#define N_USERS 200000
#define N_ITEMS 100000
#define N_NODES 300000
#define N_EDGES 4800000
#define EMB 64
#define BATCH 4096
#define NSLOTS (2 * BATCH)
#define NBITMAP ((N_NODES + 31) / 32)   // 9375 u32 = 37.5 KB
#define CAP 64                          // bucket capacity; Poisson(16) overflow P ~ 1e-18

typedef unsigned int u32;

// K1: re-init ws (harness poisons with 0xAA each call)
__global__ void k_init(int* __restrict__ node2slot, u32* __restrict__ bitmap,
                       u32* __restrict__ slot_count) {
    int i = blockIdx.x * blockDim.x + threadIdx.x;
    if (i < N_NODES) node2slot[i] = -1;
    if (i < NBITMAP) bitmap[i] = 0u;
    if (i < NSLOTS) slot_count[i] = 0u;
}

// K2: canonical slot per selected node (CAS; duplicates share winner) + membership bit
__global__ void k_map(const int* __restrict__ user_id, const int* __restrict__ item_id,
                      int* __restrict__ node2slot, u32* __restrict__ bitmap) {
    int b = blockIdx.x * blockDim.x + threadIdx.x;
    if (b >= NSLOTS) return;
    int node = (b < BATCH) ? user_id[b] : (N_USERS + item_id[b - BATCH]);
    atomicCAS(&node2slot[node], -1, b);
    atomicOr(&bitmap[node >> 5], 1u << (node & 31));
}

// K3: stream adj_row (int4 = 16B/lane), bitmap test (37.5KB, cache-hot);
// hits: spread int atomic on slot_count + 4B edge-id scatter. No f32 atomics.
__global__ void k_filter(const int4* __restrict__ adj_row4, const u32* __restrict__ bitmap,
                         const int* __restrict__ node2slot,
                         u32* __restrict__ slot_count, u32* __restrict__ slot_edges) {
    u32 i = blockIdx.x * blockDim.x + threadIdx.x;
    if (i >= N_EDGES / 4) return;
    int4 rr = adj_row4[i];
    u32 e0 = i * 4u;
    #pragma unroll
    for (int k = 0; k < 4; k++) {
        int r = (&rr.x)[k];
        if ((bitmap[r >> 5] >> (r & 31)) & 1u) {
            int s = node2slot[r];
            u32 p = atomicAdd(&slot_count[s], 1u);   // 8192 addrs, L2-hot, low contention
            if (p < CAP) slot_edges[(u32)s * CAP + p] = e0 + (u32)k;
        }
    }
}

// K4: one wave per slot. Parallel (col,val) gather by lanes j<cnt, shfl-broadcast,
// coalesced 256B emb-row loads (independent across edges), register accumulate,
// write FINAL value 2*x0+acc directly to out[slot] (slots == output rows).
__global__ void k_accum(const u32* __restrict__ slot_count, const u32* __restrict__ slot_edges,
                        const int* __restrict__ adj_col, const float* __restrict__ vals,
                        const float* __restrict__ user_emb, const float* __restrict__ item_emb,
                        const int* __restrict__ user_id, const int* __restrict__ item_id,
                        float* __restrict__ out) {
    int lane = threadIdx.x & 63;
    u32 s = (u32)(blockIdx.x * blockDim.x + threadIdx.x) >> 6;
    if (s >= NSLOTS) return;
    u32 cnt = slot_count[s];
    if (cnt > CAP) cnt = CAP;
    int c = 0; float v = 0.f;
    if ((u32)lane < cnt) {
        u32 e = slot_edges[s * CAP + (u32)lane];   // coalesced
        c = adj_col[e];                             // parallel gather
        v = vals[e];                                // parallel gather
    }
    float a0 = 0.f, a1 = 0.f;
    u32 j = 0;
    for (; j + 2 <= cnt; j += 2) {                  // 2-way for load ILP
        int c0 = __shfl(c, (int)j);     float v0 = __shfl(v, (int)j);
        int c1 = __shfl(c, (int)j + 1); float v1 = __shfl(v, (int)j + 1);
        const float* x0p = (c0 < N_USERS) ? user_emb + (size_t)c0 * EMB
                                          : item_emb + (size_t)(c0 - N_USERS) * EMB;
        const float* x1p = (c1 < N_USERS) ? user_emb + (size_t)c1 * EMB
                                          : item_emb + (size_t)(c1 - N_USERS) * EMB;
        a0 += v0 * x0p[lane];
        a1 += v1 * x1p[lane];
    }
    if (j < cnt) {
        int c0 = __shfl(c, (int)j); float v0 = __shfl(v, (int)j);
        const float* x0p = (c0 < N_USERS) ? user_emb + (size_t)c0 * EMB
                                          : item_emb + (size_t)(c0 - N_USERS) * EMB;
        a0 += v0 * x0p[lane];
    }
    int node = (s < BATCH) ? user_id[s] : (N_USERS + item_id[s - BATCH]);
    const float* xr = (node < N_USERS) ? user_emb + (size_t)node * EMB
                                       : item_emb + (size_t)(node - N_USERS) * EMB;
    out[(size_t)s * EMB + lane] = 2.f * xr[lane] + (a0 + a1);
}

// K5: duplicate ids copy their canonical row (s != o only; canonical rows already final)
__global__ void k_dup(const int* __restrict__ user_id, const int* __restrict__ item_id,
                      const int* __restrict__ node2slot, float* __restrict__ out) {
    int t = blockIdx.x * blockDim.x + threadIdx.x;
    int o = t >> 6, lane = t & 63;
    if (o >= NSLOTS) return;
    int node = (o < BATCH) ? user_id[o] : (N_USERS + item_id[o - BATCH]);
    int s = node2slot[node];
    if (s != o) out[(size_t)o * EMB + lane] = out[(size_t)s * EMB + lane];
}

extern "C" void kernel_launch(void* const* d_in, const int* in_sizes, int n_in,
                              void* d_out, int out_size, void* d_ws, size_t ws_size,
                              hipStream_t stream) {
    const float* user_emb = (const float*)d_in[0];
    const float* item_emb = (const float*)d_in[1];
    const int* adj_row = (const int*)d_in[2];
    const int* adj_col = (const int*)d_in[3];
    const float* adj_vals = (const float*)d_in[4];
    const int* user_id = (const int*)d_in[5];
    const int* item_id = (const int*)d_in[6];
    float* out = (float*)d_out;

    // ws layout (256B aligned): node2slot 1.2MB | bitmap 37.5KB | slot_count 32KB | slot_edges 2MB
    char* ws = (char*)d_ws;
    size_t off = 0;
    int* node2slot = (int*)(ws + off);  off += ((size_t)N_NODES * 4 + 255) & ~(size_t)255;
    u32* bitmap    = (u32*)(ws + off);  off += ((size_t)NBITMAP * 4 + 255) & ~(size_t)255;
    u32* slot_count= (u32*)(ws + off);  off += ((size_t)NSLOTS * 4 + 255) & ~(size_t)255;
    u32* slot_edges= (u32*)(ws + off);

    const int B = 256;
    k_init<<<(N_NODES + B - 1) / B, B, 0, stream>>>(node2slot, bitmap, slot_count);
    k_map<<<(NSLOTS + B - 1) / B, B, 0, stream>>>(user_id, item_id, node2slot, bitmap);
    k_filter<<<(N_EDGES / 4 + B - 1) / B, B, 0, stream>>>((const int4*)adj_row, bitmap,
                                                          node2slot, slot_count, slot_edges);
    k_accum<<<(NSLOTS * 64 + B - 1) / B, B, 0, stream>>>(slot_count, slot_edges, adj_col,
                                                         adj_vals, user_emb, item_emb,
                                                         user_id, item_id, out);
    k_dup<<<(NSLOTS * 64 + B - 1) / B, B, 0, stream>>>(user_id, item_id, node2slot, out);
}